// Round 5
// baseline (461.141 us; speedup 1.0000x reference)
//
#include <hip/hip_runtime.h>

// AxisAttention: x(8,256,128,128) -> per (b,w) sequence over h: QKV GEMM, 4-head
// attention (S=128, d=64), proj GEMM, transposed fp32 output.
// All matmuls: v_mfma_f32_16x16x32_f16, fp32 accum.
// A/B frag: lane l -> row/col (l&15), k read with identical expression on A and B
//           (permutation-invariant). D frag: col=l&15, row=4*(l>>4)+r [m89-verified].
// Workspace: chunked by b. Peak use = 32 MiB (qkv chunk 24 MiB + attnout 8 MiB).
// FIX vs v4: k2 Q/K staging decomposition was u>>2/u&3 (OOB rows + half-row
// uninitialized LDS -> NaN); correct is u>>3/u&7 (128 rows x 8 u4-chunks).

typedef _Float16 h4 __attribute__((ext_vector_type(4)));
typedef _Float16 h8 __attribute__((ext_vector_type(8)));
typedef float f4 __attribute__((ext_vector_type(4)));
typedef unsigned int u2 __attribute__((ext_vector_type(2)));
typedef unsigned int u4 __attribute__((ext_vector_type(4)));

#define MFMA32(a, b, c) __builtin_amdgcn_mfma_f32_16x16x32_f16((a), (b), (c), 0, 0, 0)

// ---------------- K1 (per b): qkv[f][t] = Wqkv^T[f][c] * x[b][c][h][w] + bqkv ----
// grid (h=128, 1, ft=6), block 256 = 4 waves. Tile: 128 f x 128 w, K=256.
// qkv chunk layout: [qi(3)][head(4)][w(128)][h(128)*64 + d]   (24 MiB fp16)
__global__ __launch_bounds__(256) void k1_qkv(const float* __restrict__ x,
                                              const float* __restrict__ Wqkv,
                                              const float* __restrict__ bqkv,
                                              _Float16* __restrict__ qkv,
                                              int b) {
  const int h = blockIdx.x, ft = blockIdx.z;
  const int tid = threadIdx.x;
  const int lane = tid & 63, wv = tid >> 6;
  const int g = lane >> 4, l16 = lane & 15;
  const int f0 = ft * 128;

  __shared__ __align__(16) char smem[128 * 72 * 2 * 2];  // 36864 B
  _Float16* sA = (_Float16*)smem;      // [128 f][72]
  _Float16* sB = sA + 128 * 72;        // [128 w][72]
  _Float16* sO = sA;                   // reuse: [128 w][132] = 33792 B

  f4 acc[8][2];
  for (int mt = 0; mt < 8; ++mt)
    for (int nt = 0; nt < 2; ++nt)
      for (int r = 0; r < 4; ++r) acc[mt][nt][r] = 0.f;

  for (int kc = 0; kc < 4; ++kc) {
    const int c0 = kc * 64;
    // stage A: sA[f_local][ci] = Wqkv[c0+ci][f0+f_local] (fp32 -> fp16 transpose)
    {
      const int ci = tid & 63, fblk = tid >> 6;  // fblk 0..3
#pragma unroll
      for (int i = 0; i < 8; ++i) {
        f4 v = *(const f4*)(Wqkv + (long)(c0 + ci) * 768 + f0 + fblk * 32 + i * 4);
#pragma unroll
        for (int e = 0; e < 4; ++e)
          sA[(fblk * 32 + i * 4 + e) * 72 + ci] = (_Float16)v[e];
      }
    }
    // stage B: sB[w][ci] = x[b][c0+ci][h][w] (fp32 -> fp16)
    {
      const int w4 = tid & 31, ci0 = tid >> 5;  // ci0 0..7
#pragma unroll
      for (int i = 0; i < 8; ++i) {
        int ci = i * 8 + ci0;
        const float* src = x + (((long)b * 256 + c0 + ci) * 128 + h) * 128;
#pragma unroll
        for (int j = 0; j < 4; ++j)
          sB[(j * 32 + w4) * 72 + ci] = (_Float16)src[j * 32 + w4];
      }
    }
    __syncthreads();
#pragma unroll
    for (int ks = 0; ks < 2; ++ks) {
      const int k = ks * 32 + 8 * g;
      h8 af[8], bf[2];
#pragma unroll
      for (int mt = 0; mt < 8; ++mt)
        af[mt] = *(const h8*)(sA + (mt * 16 + l16) * 72 + k);
#pragma unroll
      for (int nt = 0; nt < 2; ++nt)
        bf[nt] = *(const h8*)(sB + (wv * 32 + nt * 16 + l16) * 72 + k);
#pragma unroll
      for (int mt = 0; mt < 8; ++mt)
#pragma unroll
        for (int nt = 0; nt < 2; ++nt)
          acc[mt][nt] = MFMA32(af[mt], bf[nt], acc[mt][nt]);
    }
    __syncthreads();
  }

  // bias + repack into sO[w][f_local] (fp16)
#pragma unroll
  for (int mt = 0; mt < 8; ++mt) {
    f4 bb = *(const f4*)(bqkv + f0 + mt * 16 + 4 * g);
#pragma unroll
    for (int nt = 0; nt < 2; ++nt) {
      int wl = wv * 32 + nt * 16 + l16;
#pragma unroll
      for (int r = 0; r < 4; ++r)
        sO[wl * 132 + mt * 16 + 4 * g + r] = (_Float16)(acc[mt][nt][r] + bb[r]);
    }
  }
  __syncthreads();

  // store: qkv[qi][head][w][h*64+d]; 64B contiguous runs per (head, w)
  const int qi = ft >> 1, head01 = (ft & 1) * 2;
  const int w = tid >> 1, dh = (tid & 1) * 32;
#pragma unroll
  for (int hh = 0; hh < 2; ++hh) {
    const int head = head01 + hh;
    const _Float16* s = sO + w * 132 + hh * 64 + dh;
    _Float16* dst = qkv + ((long)(qi * 4 + head) * 128 + w) * 8192 + h * 64 + dh;
#pragma unroll
    for (int e = 0; e < 8; ++e)
      *(u2*)(dst + e * 4) = *(const u2*)(s + e * 4);
  }
}

// ---------------- K2 (per b): attention per (head, w) ----------------
// S^T = K * Q^T (per-lane-column softmax); P routed through LDS; O^T = V^T * P^T.
__global__ __launch_bounds__(256) void k2_attn(const _Float16* __restrict__ qkv,
                                               _Float16* __restrict__ attnout) {
  const int w = blockIdx.x, head = blockIdx.y;
  const int tid = threadIdx.x;
  const int lane = tid & 63, wv = tid >> 6;
  const int g = lane >> 4, l16 = lane & 15;

  __shared__ __align__(16) char smem[(128 * 72 * 2 + 64 * 136) * 2];  // 54272 B
  _Float16* sQ = (_Float16*)smem;       // [128 h][72]
  _Float16* sK = sQ + 128 * 72;         // [128 h][72]
  _Float16* sVT = sK + 128 * 72;        // [64 d][136]
  _Float16* sP = sQ;                    // reuse sQ+sK: [128 hq][136] = 34816 B
  _Float16* sO = sQ;                    // reuse: [128 h][68] = 17408 B

  const long base = ((long)(head * 128 + w)) * 8192;
  const long QS = (long)4 * 128 * 8192;  // per-tensor stride within chunk
  const _Float16* qg = qkv + base;
  const _Float16* kg = qkv + base + QS;
  const _Float16* vg = qkv + base + 2 * QS;

  // stage Q, K row-major [h][d]: 128 rows x 8 u4-chunks (64 fp16) each
#pragma unroll
  for (int i = 0; i < 4; ++i) {
    int u = tid + 256 * i;             // 0..1023
    int hh = u >> 3, dq = u & 7;       // FIXED: was u>>2 / u&3
    *(u4*)(sQ + hh * 72 + dq * 8) = *(const u4*)(qg + hh * 64 + dq * 8);
    *(u4*)(sK + hh * 72 + dq * 8) = *(const u4*)(kg + hh * 64 + dq * 8);
  }
  // stage V transposed -> sVT[d][h]
  {
    const int hh = tid & 127, dc = tid >> 7;
#pragma unroll
    for (int jj = 0; jj < 4; ++jj) {
      u4 vv = *(const u4*)(vg + hh * 64 + dc * 32 + jj * 8);
      const _Float16* pe = (const _Float16*)&vv;
#pragma unroll
      for (int e = 0; e < 8; ++e)
        sVT[(dc * 32 + jj * 8 + e) * 136 + hh] = pe[e];
    }
  }
  __syncthreads();

  // S^T[hk][hq], per wave: hq in [wv*32, wv*32+32)
  f4 accS[8][2];
  for (int i = 0; i < 8; ++i)
    for (int jt = 0; jt < 2; ++jt)
      for (int r = 0; r < 4; ++r) accS[i][jt][r] = 0.f;
#pragma unroll
  for (int ks = 0; ks < 2; ++ks) {
    const int k = ks * 32 + 8 * g;
    h8 af[8], bf[2];
#pragma unroll
    for (int i = 0; i < 8; ++i)
      af[i] = *(const h8*)(sK + (i * 16 + l16) * 72 + k);
#pragma unroll
    for (int jt = 0; jt < 2; ++jt)
      bf[jt] = *(const h8*)(sQ + (wv * 32 + jt * 16 + l16) * 72 + k);
#pragma unroll
    for (int i = 0; i < 8; ++i)
#pragma unroll
      for (int jt = 0; jt < 2; ++jt)
        accS[i][jt] = MFMA32(af[i], bf[jt], accS[i][jt]);
  }

  // softmax over hk: lane holds rows hk = i*16+4g+r of column hq(l16,jt)
  float rinv[2];
#pragma unroll
  for (int jt = 0; jt < 2; ++jt) {
    float m = -1e30f;
    for (int i = 0; i < 8; ++i)
      for (int r = 0; r < 4; ++r) m = fmaxf(m, accS[i][jt][r]);
    m = fmaxf(m, __shfl_xor(m, 16));
    m = fmaxf(m, __shfl_xor(m, 32));
    float s = 0.f;
    for (int i = 0; i < 8; ++i)
      for (int r = 0; r < 4; ++r) {
        float p = __expf((accS[i][jt][r] - m) * 0.125f);
        accS[i][jt][r] = p;
        s += p;
      }
    s += __shfl_xor(s, 16);
    s += __shfl_xor(s, 32);
    rinv[jt] = 1.0f / s;
  }

  __syncthreads();  // all waves done reading sQ/sK
  // write P (unnormalized) to sP[hq][hk] via verified D layout
#pragma unroll
  for (int jt = 0; jt < 2; ++jt) {
    const int hq = wv * 32 + jt * 16 + l16;
#pragma unroll
    for (int i = 0; i < 8; ++i) {
      h4 pv;
      pv[0] = (_Float16)accS[i][jt][0];
      pv[1] = (_Float16)accS[i][jt][1];
      pv[2] = (_Float16)accS[i][jt][2];
      pv[3] = (_Float16)accS[i][jt][3];
      *(h4*)(sP + hq * 136 + i * 16 + 4 * g) = pv;
    }
  }
  __syncthreads();

  // O^T[d][hq] = V^T * P^T, K = 128 (hk)
  f4 accO[4][2];
  for (int mt = 0; mt < 4; ++mt)
    for (int jt = 0; jt < 2; ++jt)
      for (int r = 0; r < 4; ++r) accO[mt][jt][r] = 0.f;
#pragma unroll
  for (int i2 = 0; i2 < 4; ++i2) {
    const int k = i2 * 32 + 8 * g;
    h8 av[4], pb[2];
#pragma unroll
    for (int mt = 0; mt < 4; ++mt)
      av[mt] = *(const h8*)(sVT + (mt * 16 + l16) * 136 + k);
#pragma unroll
    for (int jt = 0; jt < 2; ++jt)
      pb[jt] = *(const h8*)(sP + (wv * 32 + jt * 16 + l16) * 136 + k);
#pragma unroll
    for (int mt = 0; mt < 4; ++mt)
#pragma unroll
      for (int jt = 0; jt < 2; ++jt)
        accO[mt][jt] = MFMA32(av[mt], pb[jt], accO[mt][jt]);
  }

  __syncthreads();  // all waves done reading sP
  // normalize + repack to sO[h][d]
#pragma unroll
  for (int mt = 0; mt < 4; ++mt)
#pragma unroll
    for (int jt = 0; jt < 2; ++jt)
#pragma unroll
      for (int r = 0; r < 4; ++r)
        sO[(wv * 32 + jt * 16 + l16) * 68 + mt * 16 + 4 * g + r] =
            (_Float16)(accO[mt][jt][r] * rinv[jt]);
  __syncthreads();

  // store attnout[(h*128 + w)][head*64 + d]  (t local to this b)
  const int hh = tid >> 1, dh = (tid & 1) * 32;
  const _Float16* s = sO + hh * 68 + dh;
  _Float16* dst = attnout + ((long)(hh * 128 + w)) * 256 + head * 64 + dh;
#pragma unroll
  for (int e = 0; e < 8; ++e)
    *(u2*)(dst + e * 4) = *(const u2*)(s + e * 4);
}

// ---------------- K3 (per b): out[b][co][t] = Wproj^T[co][c]*attnout[t][c]+bproj --
// grid (tt=128, ct=2), tile 128 co x 128 t, K=256. t = h*128+w (h = tt fixed).
__global__ __launch_bounds__(256) void k3_proj(const _Float16* __restrict__ attnout,
                                               const float* __restrict__ Wproj,
                                               const float* __restrict__ bproj,
                                               float* __restrict__ out,
                                               int b) {
  const int tt = blockIdx.x, ct = blockIdx.y;
  const int tid = threadIdx.x;
  const int lane = tid & 63, wv = tid >> 6;
  const int g = lane >> 4, l16 = lane & 15;
  const int co0 = ct * 128;
  const long t0 = (long)tt * 128;

  __shared__ __align__(16) char smem[128 * 72 * 2 * 2];  // 36864 B
  _Float16* sA = (_Float16*)smem;     // [128 co][72]
  _Float16* sB = sA + 128 * 72;       // [128 t][72]

  f4 acc[8][2];
  for (int mt = 0; mt < 8; ++mt)
    for (int nt = 0; nt < 2; ++nt)
      for (int r = 0; r < 4; ++r) acc[mt][nt][r] = 0.f;

  const _Float16* Bb = attnout + t0 * 256;

  for (int kc = 0; kc < 4; ++kc) {
    const int c0 = kc * 64;
    // stage A: sA[co_local][ci] = Wproj[c0+ci][co0+co_local]
    {
      const int ci = tid & 63, coblk = tid >> 6;
#pragma unroll
      for (int i = 0; i < 8; ++i) {
        f4 v = *(const f4*)(Wproj + (long)(c0 + ci) * 256 + co0 + coblk * 32 + i * 4);
#pragma unroll
        for (int e = 0; e < 4; ++e)
          sA[(coblk * 32 + i * 4 + e) * 72 + ci] = (_Float16)v[e];
      }
    }
    // stage B: row-major fp16 copy (pitch 72 -> 16B-aligned b128 writes)
#pragma unroll
    for (int i = 0; i < 4; ++i) {
      int u = tid + 256 * i;
      int row = u >> 3, cc = u & 7;
      *(u4*)(sB + row * 72 + cc * 8) = *(const u4*)(Bb + (long)row * 256 + c0 + cc * 8);
    }
    __syncthreads();
#pragma unroll
    for (int ks = 0; ks < 2; ++ks) {
      const int k = ks * 32 + 8 * g;
      h8 af[8], bf[2];
#pragma unroll
      for (int mt = 0; mt < 8; ++mt)
        af[mt] = *(const h8*)(sA + (mt * 16 + l16) * 72 + k);
#pragma unroll
      for (int nt = 0; nt < 2; ++nt)
        bf[nt] = *(const h8*)(sB + (wv * 32 + nt * 16 + l16) * 72 + k);
#pragma unroll
      for (int mt = 0; mt < 8; ++mt)
#pragma unroll
        for (int nt = 0; nt < 2; ++nt)
          acc[mt][nt] = MFMA32(af[mt], bf[nt], acc[mt][nt]);
    }
    __syncthreads();
  }

#pragma unroll
  for (int mt = 0; mt < 8; ++mt) {
    f4 bb = *(const f4*)(bproj + co0 + mt * 16 + 4 * g);
#pragma unroll
    for (int nt = 0; nt < 2; ++nt)
#pragma unroll
      for (int r = 0; r < 4; ++r) {
        long co = co0 + mt * 16 + 4 * g + r;
        out[((long)b * 256 + co) * 16384 + t0 + wv * 32 + nt * 16 + l16] =
            acc[mt][nt][r] + bb[r];
      }
  }
}

// ---------------- launch ----------------
extern "C" void kernel_launch(void* const* d_in, const int* in_sizes, int n_in,
                              void* d_out, int out_size, void* d_ws, size_t ws_size,
                              hipStream_t stream) {
  const float* x = (const float*)d_in[0];
  const float* Wqkv = (const float*)d_in[1];
  const float* bqkv = (const float*)d_in[2];
  const float* Wproj = (const float*)d_in[3];
  const float* bproj = (const float*)d_in[4];
  float* out = (float*)d_out;

  char* ws = (char*)d_ws;
  // Peak workspace 32 MiB:
  // [0, 24M):   qkv chunk fp16 [3][4][128 w][128 h * 64 d]  (one b at a time)
  // [24M, 32M): attnout chunk fp16 [t=h*128+w][256]
  _Float16* qkv = (_Float16*)ws;
  _Float16* attnout = (_Float16*)(ws + 25165824L);

  for (int b = 0; b < 8; ++b) {
    k1_qkv<<<dim3(128, 1, 6), 256, 0, stream>>>(x, Wqkv, bqkv, qkv, b);
    k2_attn<<<dim3(128, 4), 256, 0, stream>>>(qkv, attnout);
    k3_proj<<<dim3(128, 2), 256, 0, stream>>>(attnout, Wproj, bproj, out, b);
  }
}

// Round 6
// 316.550 us; speedup vs baseline: 1.4568x; 1.4568x over previous
//
#include <hip/hip_runtime.h>

// AxisAttention: x(8,256,128,128) -> per (b,w) sequence over h: QKV GEMM, 4-head
// attention (S=128, d=64), proj GEMM, transposed fp32 output.
// All matmuls: v_mfma_f32_16x16x32_f16, fp32 accum.
// A/B frag: lane l -> row/col (l&15), k read with identical expression on A and B.
// D frag:   col=l&15, row=4*(l>>4)+r [m89-verified].
// v6: un-chunked (nb batches/pass, adaptive to ws_size), prep'd fp16 W^T,
//     XCD-swizzled k1 grid, u4/f4 coalesced epilogues (k3 via LDS repack).

typedef _Float16 h4 __attribute__((ext_vector_type(4)));
typedef _Float16 h8 __attribute__((ext_vector_type(8)));
typedef float f4 __attribute__((ext_vector_type(4)));
typedef unsigned int u4 __attribute__((ext_vector_type(4)));

#define MFMA32(a, b, c) __builtin_amdgcn_mfma_f32_16x16x32_f16((a), (b), (c), 0, 0, 0)

// ---------------- prep: W^T fp16 (wqt[f][c], wpt[f][c]) ----------------
__global__ __launch_bounds__(256) void prep_w(const float* __restrict__ Wqkv,
                                              const float* __restrict__ Wproj,
                                              _Float16* __restrict__ wqt,
                                              _Float16* __restrict__ wpt) {
  int i = blockIdx.x * 256 + threadIdx.x;  // 196608 + 65536
  if (i < 768 * 256) {
    int f = i >> 8, c = i & 255;
    wqt[i] = (_Float16)Wqkv[c * 768 + f];
  } else {
    int j = i - 768 * 256;
    int f = j >> 8, c = j & 255;
    wpt[j] = (_Float16)Wproj[c * 256 + f];
  }
}

// ---------------- K1: qkv[f][t] = Wqkv^T[f][c] * x[b][c][h][w] + bqkv ----------
// 1D grid nbv*768, XCD-swizzled so the 6 ft-blocks of one (h,bl) group are
// consecutive on one XCD (x-slice L2 reuse). Tile 128f x 128w, K=256, 4 waves.
// qkv layout: [qi][bl][head][w][h*64+d]  (contiguous 16KB per (head,w))
template <bool PREPPED>
__global__ __launch_bounds__(256) void k1_qkv(const float* __restrict__ x,
                                              const float* __restrict__ Wqkv,
                                              const _Float16* __restrict__ wqt,
                                              const float* __restrict__ bqkv,
                                              _Float16* __restrict__ qkv,
                                              int b_base, int nb) {
  // decode swizzled block id: xcd = wg&7 (assumed HW round-robin), per-XCD
  // sequence enumerates (group, ft) with ft fastest.
  const int wg = blockIdx.x;
  const int xcd = wg & 7, gseq = wg >> 3;
  const int ft = gseq % 6, Ghi = gseq / 6;
  const int G = Ghi * 8 + xcd;          // G in [0, nbv*128)
  const int h = G & 127, bl = G >> 7;
  const int b = b_base + bl;

  const int tid = threadIdx.x;
  const int lane = tid & 63, wv = tid >> 6;
  const int g = lane >> 4, l16 = lane & 15;
  const int f0 = ft * 128;

  __shared__ __align__(16) char smem[128 * 72 * 2 * 2];  // 36864 B
  _Float16* sA = (_Float16*)smem;      // [128 f][72]
  _Float16* sB = sA + 128 * 72;        // [128 w][72]
  _Float16* sO = sA;                   // reuse: [128 w][136] = 34816 B

  f4 acc[8][2];
  for (int mt = 0; mt < 8; ++mt)
    for (int nt = 0; nt < 2; ++nt)
      for (int r = 0; r < 4; ++r) acc[mt][nt][r] = 0.f;

  for (int kc = 0; kc < 4; ++kc) {
    const int c0 = kc * 64;
    // stage A
    if (PREPPED) {
#pragma unroll
      for (int i = 0; i < 4; ++i) {
        int u = tid + 256 * i;
        int row = u >> 3, cc = u & 7;
        *(u4*)(sA + row * 72 + cc * 8) =
            *(const u4*)(wqt + (long)(f0 + row) * 256 + c0 + cc * 8);
      }
    } else {
      const int ci = tid & 63, fblk = tid >> 6;
#pragma unroll
      for (int i = 0; i < 8; ++i) {
        f4 v = *(const f4*)(Wqkv + (long)(c0 + ci) * 768 + f0 + fblk * 32 + i * 4);
#pragma unroll
        for (int e = 0; e < 4; ++e)
          sA[(fblk * 32 + i * 4 + e) * 72 + ci] = (_Float16)v[e];
      }
    }
    // stage B: sB[w][ci] = x[b][c0+ci][h][w]
    {
      const int w4 = tid & 31, ci0 = tid >> 5;
#pragma unroll
      for (int i = 0; i < 8; ++i) {
        int ci = i * 8 + ci0;
        const float* src = x + (((long)b * 256 + c0 + ci) * 128 + h) * 128;
#pragma unroll
        for (int j = 0; j < 4; ++j)
          sB[(j * 32 + w4) * 72 + ci] = (_Float16)src[j * 32 + w4];
      }
    }
    __syncthreads();
#pragma unroll
    for (int ks = 0; ks < 2; ++ks) {
      const int k = ks * 32 + 8 * g;
      h8 af[8], bf[2];
#pragma unroll
      for (int mt = 0; mt < 8; ++mt)
        af[mt] = *(const h8*)(sA + (mt * 16 + l16) * 72 + k);
#pragma unroll
      for (int nt = 0; nt < 2; ++nt)
        bf[nt] = *(const h8*)(sB + (wv * 32 + nt * 16 + l16) * 72 + k);
#pragma unroll
      for (int mt = 0; mt < 8; ++mt)
#pragma unroll
        for (int nt = 0; nt < 2; ++nt)
          acc[mt][nt] = MFMA32(af[mt], bf[nt], acc[mt][nt]);
    }
    __syncthreads();
  }

  // bias + repack into sO[w][f_local] (pitch 136 -> u4-aligned rows)
#pragma unroll
  for (int mt = 0; mt < 8; ++mt) {
    f4 bb = *(const f4*)(bqkv + f0 + mt * 16 + 4 * g);
#pragma unroll
    for (int nt = 0; nt < 2; ++nt) {
      int wl = wv * 32 + nt * 16 + l16;
#pragma unroll
      for (int r = 0; r < 4; ++r)
        sO[wl * 136 + mt * 16 + 4 * g + r] = (_Float16)(acc[mt][nt][r] + bb[r]);
    }
  }
  __syncthreads();

  // store: qkv[(qi*nb+bl)*4+head][w][h*64+d]; 128B segments (lane-pair contig)
  const int qi = ft >> 1, head01 = (ft & 1) * 2;
  const int w = tid >> 1, d0 = (tid & 1) * 32;
#pragma unroll
  for (int hh = 0; hh < 2; ++hh) {
    const int head = head01 + hh;
    const _Float16* s = sO + w * 136 + hh * 64 + d0;
    _Float16* dst = qkv + (((long)(qi * nb + bl) * 4 + head) * 128 + w) * 8192 +
                    h * 64 + d0;
#pragma unroll
    for (int e = 0; e < 4; ++e)
      *(u4*)(dst + e * 8) = *(const u4*)(s + e * 8);
  }
}

// ---------------- K2: attention per (w, head, bl) ----------------
__global__ __launch_bounds__(256) void k2_attn(const _Float16* __restrict__ qkv,
                                               _Float16* __restrict__ attnout,
                                               int nb) {
  const int w = blockIdx.x, head = blockIdx.y, bl = blockIdx.z;
  const int tid = threadIdx.x;
  const int lane = tid & 63, wv = tid >> 6;
  const int g = lane >> 4, l16 = lane & 15;

  __shared__ __align__(16) char smem[(128 * 72 * 2 + 64 * 136) * 2];  // 54272 B
  _Float16* sQ = (_Float16*)smem;       // [128 h][72]
  _Float16* sK = sQ + 128 * 72;         // [128 h][72]
  _Float16* sVT = sK + 128 * 72;        // [64 d][136]
  _Float16* sP = sQ;                    // reuse: [128 hq][136]
  _Float16* sO = sQ;                    // reuse: [128 h][72]

  const long base = (((long)(0 * nb + bl) * 4 + head) * 128 + w) * 8192;
  const long QS = (long)nb * 4 * 128 * 8192;  // qi stride
  const _Float16* qg = qkv + base;
  const _Float16* kg = qkv + base + QS;
  const _Float16* vg = qkv + base + 2 * QS;

  // stage Q, K row-major [h][d]: 128 rows x 8 u4-chunks
#pragma unroll
  for (int i = 0; i < 4; ++i) {
    int u = tid + 256 * i;
    int hh = u >> 3, dq = u & 7;
    *(u4*)(sQ + hh * 72 + dq * 8) = *(const u4*)(qg + hh * 64 + dq * 8);
    *(u4*)(sK + hh * 72 + dq * 8) = *(const u4*)(kg + hh * 64 + dq * 8);
  }
  // stage V transposed -> sVT[d][h]
  {
    const int hh = tid & 127, dc = tid >> 7;
#pragma unroll
    for (int jj = 0; jj < 4; ++jj) {
      u4 vv = *(const u4*)(vg + hh * 64 + dc * 32 + jj * 8);
      const _Float16* pe = (const _Float16*)&vv;
#pragma unroll
      for (int e = 0; e < 8; ++e)
        sVT[(dc * 32 + jj * 8 + e) * 136 + hh] = pe[e];
    }
  }
  __syncthreads();

  // S^T[hk][hq], per wave: hq in [wv*32, wv*32+32)
  f4 accS[8][2];
  for (int i = 0; i < 8; ++i)
    for (int jt = 0; jt < 2; ++jt)
      for (int r = 0; r < 4; ++r) accS[i][jt][r] = 0.f;
#pragma unroll
  for (int ks = 0; ks < 2; ++ks) {
    const int k = ks * 32 + 8 * g;
    h8 af[8], bf[2];
#pragma unroll
    for (int i = 0; i < 8; ++i)
      af[i] = *(const h8*)(sK + (i * 16 + l16) * 72 + k);
#pragma unroll
    for (int jt = 0; jt < 2; ++jt)
      bf[jt] = *(const h8*)(sQ + (wv * 32 + jt * 16 + l16) * 72 + k);
#pragma unroll
    for (int i = 0; i < 8; ++i)
#pragma unroll
      for (int jt = 0; jt < 2; ++jt)
        accS[i][jt] = MFMA32(af[i], bf[jt], accS[i][jt]);
  }

  // softmax over hk (per-lane column + shfl 16/32)
  float rinv[2];
#pragma unroll
  for (int jt = 0; jt < 2; ++jt) {
    float m = -1e30f;
    for (int i = 0; i < 8; ++i)
      for (int r = 0; r < 4; ++r) m = fmaxf(m, accS[i][jt][r]);
    m = fmaxf(m, __shfl_xor(m, 16));
    m = fmaxf(m, __shfl_xor(m, 32));
    float s = 0.f;
    for (int i = 0; i < 8; ++i)
      for (int r = 0; r < 4; ++r) {
        float p = __expf((accS[i][jt][r] - m) * 0.125f);
        accS[i][jt][r] = p;
        s += p;
      }
    s += __shfl_xor(s, 16);
    s += __shfl_xor(s, 32);
    rinv[jt] = 1.0f / s;
  }

  __syncthreads();  // done reading sQ/sK
  // write P (unnormalized) to sP[hq][hk] via verified D layout
#pragma unroll
  for (int jt = 0; jt < 2; ++jt) {
    const int hq = wv * 32 + jt * 16 + l16;
#pragma unroll
    for (int i = 0; i < 8; ++i) {
      h4 pv;
      pv[0] = (_Float16)accS[i][jt][0];
      pv[1] = (_Float16)accS[i][jt][1];
      pv[2] = (_Float16)accS[i][jt][2];
      pv[3] = (_Float16)accS[i][jt][3];
      *(h4*)(sP + hq * 136 + i * 16 + 4 * g) = pv;
    }
  }
  __syncthreads();

  // O^T[d][hq] = V^T * P^T, K = 128
  f4 accO[4][2];
  for (int mt = 0; mt < 4; ++mt)
    for (int jt = 0; jt < 2; ++jt)
      for (int r = 0; r < 4; ++r) accO[mt][jt][r] = 0.f;
#pragma unroll
  for (int i2 = 0; i2 < 4; ++i2) {
    const int k = i2 * 32 + 8 * g;
    h8 av[4], pb[2];
#pragma unroll
    for (int mt = 0; mt < 4; ++mt)
      av[mt] = *(const h8*)(sVT + (mt * 16 + l16) * 136 + k);
#pragma unroll
    for (int jt = 0; jt < 2; ++jt)
      pb[jt] = *(const h8*)(sP + (wv * 32 + jt * 16 + l16) * 136 + k);
#pragma unroll
    for (int mt = 0; mt < 4; ++mt)
#pragma unroll
      for (int jt = 0; jt < 2; ++jt)
        accO[mt][jt] = MFMA32(av[mt], pb[jt], accO[mt][jt]);
  }

  __syncthreads();  // done reading sP
  // normalize + repack to sO[h][d] (pitch 72)
#pragma unroll
  for (int mt = 0; mt < 4; ++mt)
#pragma unroll
    for (int jt = 0; jt < 2; ++jt)
#pragma unroll
      for (int r = 0; r < 4; ++r)
        sO[(wv * 32 + jt * 16 + l16) * 72 + mt * 16 + 4 * g + r] =
            (_Float16)(accO[mt][jt][r] * rinv[jt]);
  __syncthreads();

  // store attnout[bl][(h*128 + w)][head*64 + d] as u4s
  const int hh = tid >> 1, d0 = (tid & 1) * 32;
  const _Float16* s = sO + hh * 72 + d0;
  _Float16* dst = attnout + ((long)bl * 16384 + hh * 128 + w) * 256 + head * 64 + d0;
#pragma unroll
  for (int e = 0; e < 4; ++e)
    *(u4*)(dst + e * 8) = *(const u4*)(s + e * 8);
}

// ---------------- K3: out[b][co][t] = Wproj^T[co][c]*attnout[t][c]+bproj --------
// grid (ct=2, tt=128, bl): ct fastest so the two co-tiles sharing a B tile pair.
template <bool PREPPED>
__global__ __launch_bounds__(256) void k3_proj(const _Float16* __restrict__ attnout,
                                               const float* __restrict__ Wproj,
                                               const _Float16* __restrict__ wpt,
                                               const float* __restrict__ bproj,
                                               float* __restrict__ out,
                                               int b_base, int nb) {
  const int ct = blockIdx.x, tt = blockIdx.y, bl = blockIdx.z;
  const int b = b_base + bl;
  const int tid = threadIdx.x;
  const int lane = tid & 63, wv = tid >> 6;
  const int g = lane >> 4, l16 = lane & 15;
  const int co0 = ct * 128;
  const long t0 = (long)tt * 128;

  __shared__ __align__(16) char smem[128 * 72 * 2 * 2];  // 36864 B
  _Float16* sA = (_Float16*)smem;     // [128 co][72]
  _Float16* sB = sA + 128 * 72;       // [128 t][72]
  float* sOut = (float*)smem;         // reuse: [64][132] f32 = 33792 B

  f4 acc[8][2];
  for (int mt = 0; mt < 8; ++mt)
    for (int nt = 0; nt < 2; ++nt)
      for (int r = 0; r < 4; ++r) acc[mt][nt][r] = 0.f;

  const _Float16* Bb = attnout + ((long)bl * 16384 + t0) * 256;

  for (int kc = 0; kc < 4; ++kc) {
    const int c0 = kc * 64;
    if (PREPPED) {
#pragma unroll
      for (int i = 0; i < 4; ++i) {
        int u = tid + 256 * i;
        int row = u >> 3, cc = u & 7;
        *(u4*)(sA + row * 72 + cc * 8) =
            *(const u4*)(wpt + (long)(co0 + row) * 256 + c0 + cc * 8);
      }
    } else {
      const int ci = tid & 63, coblk = tid >> 6;
#pragma unroll
      for (int i = 0; i < 8; ++i) {
        f4 v = *(const f4*)(Wproj + (long)(c0 + ci) * 256 + co0 + coblk * 32 + i * 4);
#pragma unroll
        for (int e = 0; e < 4; ++e)
          sA[(coblk * 32 + i * 4 + e) * 72 + ci] = (_Float16)v[e];
      }
    }
#pragma unroll
    for (int i = 0; i < 4; ++i) {
      int u = tid + 256 * i;
      int row = u >> 3, cc = u & 7;
      *(u4*)(sB + row * 72 + cc * 8) = *(const u4*)(Bb + (long)row * 256 + c0 + cc * 8);
    }
    __syncthreads();
#pragma unroll
    for (int ks = 0; ks < 2; ++ks) {
      const int k = ks * 32 + 8 * g;
      h8 af[8], bf[2];
#pragma unroll
      for (int mt = 0; mt < 8; ++mt)
        af[mt] = *(const h8*)(sA + (mt * 16 + l16) * 72 + k);
#pragma unroll
      for (int nt = 0; nt < 2; ++nt)
        bf[nt] = *(const h8*)(sB + (wv * 32 + nt * 16 + l16) * 72 + k);
#pragma unroll
      for (int mt = 0; mt < 8; ++mt)
#pragma unroll
        for (int nt = 0; nt < 2; ++nt)
          acc[mt][nt] = MFMA32(af[mt], bf[nt], acc[mt][nt]);
    }
    __syncthreads();
  }

  // epilogue: repack halves through LDS, write 512B-contiguous fp32 rows
#pragma unroll
  for (int half = 0; half < 2; ++half) {
    if (half) __syncthreads();  // first sync already done above
#pragma unroll
    for (int mt2 = 0; mt2 < 4; ++mt2) {
      const int mt = half * 4 + mt2;
      f4 bb = *(const f4*)(bproj + co0 + mt * 16 + 4 * g);
#pragma unroll
      for (int nt = 0; nt < 2; ++nt)
#pragma unroll
        for (int r = 0; r < 4; ++r)
          sOut[(mt2 * 16 + 4 * g + r) * 132 + wv * 32 + nt * 16 + l16] =
              acc[mt][nt][r] + bb[r];
    }
    __syncthreads();
    const int row = tid >> 2, seg = (tid & 3) * 32;
    const float* s = sOut + row * 132 + seg;
    float* dst = out + ((long)b * 256 + co0 + half * 64 + row) * 16384 + t0 + seg;
#pragma unroll
    for (int e = 0; e < 8; ++e)
      *(f4*)(dst + e * 4) = *(const f4*)(s + e * 4);
  }
}

// ---------------- launch ----------------
extern "C" void kernel_launch(void* const* d_in, const int* in_sizes, int n_in,
                              void* d_out, int out_size, void* d_ws, size_t ws_size,
                              hipStream_t stream) {
  const float* x = (const float*)d_in[0];
  const float* Wqkv = (const float*)d_in[1];
  const float* bqkv = (const float*)d_in[2];
  const float* Wproj = (const float*)d_in[3];
  const float* bproj = (const float*)d_in[4];
  float* out = (float*)d_out;

  char* ws = (char*)d_ws;
  // Layout (PREPPED): [wqt 384K][wpt 128K][qkv nb*24Mi][attnout nb*8Mi]
  const long WQT = 393216L, WPT = 131072L;
  const long PER_B = 33554432L;  // 24Mi qkv + 8Mi attnout
  long nb_l = ((long)ws_size - (WQT + WPT)) / PER_B;
  bool prepped = nb_l >= 1;
  int nb = prepped ? (int)(nb_l > 8 ? 8 : nb_l) : 1;  // fallback: v5-proven 32MiB

  _Float16* wqt;
  _Float16* wpt;
  _Float16* qkv;
  _Float16* attnout;
  if (prepped) {
    wqt = (_Float16*)ws;
    wpt = (_Float16*)(ws + WQT);
    qkv = (_Float16*)(ws + WQT + WPT);
    attnout = (_Float16*)(ws + WQT + WPT + (long)nb * 25165824L);
    prep_w<<<1024, 256, 0, stream>>>(Wqkv, Wproj, wqt, wpt);
  } else {
    wqt = wpt = nullptr;
    qkv = (_Float16*)ws;
    attnout = (_Float16*)(ws + (long)nb * 25165824L);
  }

  for (int b0 = 0; b0 < 8; b0 += nb) {
    int nbv = (8 - b0 < nb) ? (8 - b0) : nb;
    if (prepped) {
      k1_qkv<true><<<nbv * 768, 256, 0, stream>>>(x, Wqkv, wqt, bqkv, qkv, b0, nbv);
      k2_attn<<<dim3(128, 4, nbv), 256, 0, stream>>>(qkv, attnout, nbv);
      k3_proj<true><<<dim3(2, 128, nbv), 256, 0, stream>>>(attnout, Wproj, wpt,
                                                           bproj, out, b0, nbv);
    } else {
      k1_qkv<false><<<nbv * 768, 256, 0, stream>>>(x, Wqkv, wqt, bqkv, qkv, b0, nbv);
      k2_attn<<<dim3(128, 4, nbv), 256, 0, stream>>>(qkv, attnout, nbv);
      k3_proj<false><<<dim3(2, 128, nbv), 256, 0, stream>>>(attnout, Wproj, wpt,
                                                            bproj, out, b0, nbv);
    }
  }
}